// Round 10
// baseline (635.077 us; speedup 1.0000x reference)
//
#include <hip/hip_runtime.h>
#include <hip/hip_bf16.h>

typedef __hip_bfloat16 bf16;
typedef __attribute__((ext_vector_type(8))) short short8;
typedef __attribute__((ext_vector_type(4))) float f32x4;

#define NN 4096
#define L2E 1.4426950408889634f

__device__ inline float br_sum(float v, float* sd){
  int t = threadIdx.x;
  sd[t] = v; __syncthreads();
  for(int s=128; s>0; s>>=1){ if(t<s) sd[t]+=sd[t+s]; __syncthreads(); }
  float r = sd[0]; __syncthreads();
  return r;
}

// async global->LDS, 16B per lane; lds base wave-uniform (HW adds lane*16)
__device__ inline void gl2lds(const bf16* g, unsigned int* lds){
  __builtin_amdgcn_global_load_lds(
      (const __attribute__((address_space(1))) unsigned int*)g,
      (__attribute__((address_space(3))) unsigned int*)lds, 16, 0, 0);
}

// wait until <= N of this thread's vmem ops outstanding
template<int N> __device__ inline void waitvm(){
  if constexpr (N==0)       asm volatile("s_waitcnt vmcnt(0)" ::: "memory");
  else if constexpr (N==6)  asm volatile("s_waitcnt vmcnt(6)" ::: "memory");
  else if constexpr (N==8)  asm volatile("s_waitcnt vmcnt(8)" ::: "memory");
  else if constexpr (N==18) asm volatile("s_waitcnt vmcnt(18)" ::: "memory");
}
__device__ inline void pipe_barrier(){
  __builtin_amdgcn_s_barrier();
  asm volatile("" ::: "memory");
}

// ---------------------------------------------------------------------------
// fused prep: blocks 0..8191 cvt df->bf16; 8192.. weight transposes
// ---------------------------------------------------------------------------
__global__ __launch_bounds__(256)
void prep_all_k(const float* __restrict__ df, const float* __restrict__ W1,
                const float* __restrict__ W2, const float* __restrict__ lw,
                bf16* __restrict__ dfb, bf16* __restrict__ W1tb,
                bf16* __restrict__ W2tb, bf16* __restrict__ lwcat)
{
  int b = blockIdx.x, t = threadIdx.x;
  if (b < 8192){
    int i = (b*256 + t)*4;
    f32x4 v = *(const f32x4*)(df + i);
    #pragma unroll
    for(int q=0;q<4;q++) dfb[i+q] = __float2bfloat16(v[q]);
    return;
  }
  b -= 8192;
  const float* src; bf16* dst; int rb, cb, dstld; bool dup=false;
  if (b < 512){            src=W1; dst=W1tb;  rb=(b>>4)<<6; cb=(b&15)<<6; dstld=2048; }
  else if (b < 768){ b-=512; src=W2; dst=W2tb; rb=(b>>4)<<6; cb=(b&15)<<6; dstld=1024; }
  else { b-=768; src=lw; dst=lwcat; rb=(b>>4)<<6; cb=(b&15)<<6; dstld=3072; dup=(rb>=2048); }
  __shared__ bf16 tile[64][65];
  #pragma unroll
  for(int i=0;i<16;i++){
    int lin=i*256+t, tr=lin>>6, tc=lin&63;
    tile[tr][tc] = __float2bfloat16(src[(size_t)(rb+tr)*1024 + cb+tc]);
  }
  __syncthreads();
  #pragma unroll
  for(int i=0;i<16;i++){
    int lin=i*256+t, tc=lin>>6, tr=lin&63;
    bf16 v = tile[tr][tc];
    dst[(size_t)(cb+tc)*dstld + rb+tr] = v;
    if(dup) dst[(size_t)(cb+tc)*dstld + rb+tr + 512] = v;
  }
}

// ---------------------------------------------------------------------------
// symmetric adjacency: 528 upper-tri 128x128 blocks of sign(df@df^T),
// 4-deep pipelined staging, XOR bank-swizzle, mirror-packed epilogue.
// ---------------------------------------------------------------------------
__global__ __launch_bounds__(256)
void adjsym_k(const bf16* __restrict__ A, unsigned int* __restrict__ Cm)
{
  __shared__ unsigned int As[4*2048];
  __shared__ unsigned int Bs[4*2048];
  const int tid = threadIdx.x;
  int idx = blockIdx.x;
  int by = (int)((65.0f - sqrtf(4225.0f - 8.0f*(float)idx)) * 0.5f);
  while ((by+1)*(65-(by+1))/2 <= idx) by++;
  while (by*(65-by)/2 > idx) by--;
  int bx = by + (idx - by*(65-by)/2);
  const int bm = by*128, bn = bx*128;
  const int lane = tid&63, wid = tid>>6;
  const int wr = (wid>>1)*64, wc = (wid&1)*64;
  const int quad = lane>>4, mr = lane&15;
  const int L4 = lane>>2, Lc = lane&3;
  const int sws = ((L4&3) ^ ((L4>>2)&3));      // staging col swizzle
  const int swr = ((mr&3) ^ ((mr>>2)&3));      // frag-read swizzle

  f32x4 acc[4][4];
  #pragma unroll
  for(int i=0;i<4;i++)
    #pragma unroll
    for(int j=0;j<4;j++) acc[i][j] = (f32x4){0.f,0.f,0.f,0.f};

  auto stage = [&](int kb, int p){
    #pragma unroll
    for(int c2=0; c2<2; c2++){
      int row = (wid*2+c2)*16 + L4;
      gl2lds(A + (size_t)(bm+row)*2048 + kb + (Lc^sws)*8, &As[p*2048 + (wid*2+c2)*256]);
      gl2lds(A + (size_t)(bn+row)*2048 + kb + (Lc^sws)*8, &Bs[p*2048 + (wid*2+c2)*256]);
    }
  };
  auto compute = [&](int p){
    short8 af[4], bfr[4];
    #pragma unroll
    for(int i=0;i<4;i++)
      af[i]  = *(const short8*)&As[p*2048 + (wr + i*16 + mr)*16 + ((quad^swr)*4)];
    #pragma unroll
    for(int j=0;j<4;j++)
      bfr[j] = *(const short8*)&Bs[p*2048 + (wc + j*16 + mr)*16 + ((quad^swr)*4)];
    #pragma unroll
    for(int i=0;i<4;i++)
      #pragma unroll
      for(int j=0;j<4;j++)
        acc[i][j] = __builtin_amdgcn_mfma_f32_16x16x32_bf16(af[i], bfr[j], acc[i][j], 0,0,0);
  };

  stage(0,0); stage(32,1); stage(64,2);
  int p = 0;
  #pragma unroll 1
  for(int it=0; it<61; it++){                  // NIT=64, NS=4
    waitvm<8>();                               // (NS-2)*D, D=4
    pipe_barrier();
    stage(32*(it+3), (p+3)&3);
    compute(p); p=(p+1)&3;
  }
  waitvm<0>(); pipe_barrier();
  #pragma unroll 1
  for(int r=0; r<3; r++){ compute(p); p=(p+1)&3; }

  #pragma unroll
  for(int i=0;i<4;i++){
    #pragma unroll
    for(int j=0;j<4;j++){
      int cbase = bn + wc + j*16;
      unsigned long long b[4];
      #pragma unroll
      for(int reg=0; reg<4; reg++){
        float v = acc[i][j][reg];
        unsigned long long msk = __ballot(v > 0.f);
        b[reg] = msk;
        if (mr == 0){                       // direct: row r, 16 cols
          int r = bm + wr + i*16 + quad*4 + reg;
          unsigned int x = (unsigned int)(msk >> (quad*16)) & 0xFFFFu;
          x = (x | (x << 8)) & 0x00FF00FFu;
          x = (x | (x << 4)) & 0x0F0F0F0Fu;
          x = (x | (x << 2)) & 0x33333333u;
          x = (x | (x << 1)) & 0x55555555u;
          if (r >= cbase && r < cbase + 16) x += 1u << (2*(r - cbase));
          Cm[(size_t)r*256 + (cbase>>4)] = x;
        }
      }
      if (bx > by){                         // mirror: row c (transposed bits)
        unsigned int x = 0;
        #pragma unroll
        for(int reg=0; reg<4; reg++){
          unsigned long long t = (b[reg] >> mr) & 0x0001000100010001ULL;
          unsigned int f = (unsigned int)((t | (t>>15) | (t>>30) | (t>>45)) & 0xFULL);
          x |= ((f&1u) | ((f&2u)<<7) | ((f&4u)<<14) | ((f&8u)<<21)) << (2*reg);
        }
        if (quad == 0){
          int c = cbase + mr;
          Cm[(size_t)c*256 + ((bm + wr + i*16)>>4)] = x;
        }
      }
    }
  }
}

// ---------------------------------------------------------------------------
// MFMA GEMM, C = A @ Bt^T.  128 x TN tile, 4 waves, NS-deep pipelined async
// staging (manual vmcnt), XOR bank-swizzle, XCD-aware block swizzle.
// DUALA: A -> Ag2 at k>=K1.  WT: also emit transposed bf16 copy to Ct.
// EPI: 1 relu->bf16 | 2 bf16 | 4 f32 +bias+leaky0.01.
// ---------------------------------------------------------------------------
template<int EPI, int TN, int DUALA, int K, int LDA, int LDBT, int LDC,
         int K1, int LDA2, int WT, int NS>
__global__ __launch_bounds__(256)
void gemm_k(const bf16* __restrict__ Ag, const bf16* __restrict__ Bt,
            void* __restrict__ Cv, const float* __restrict__ bias,
            const bf16* __restrict__ Ag2, bf16* __restrict__ Ct)
{
  constexpr int NJ  = TN/32;
  constexpr int D   = 2 + TN/64;     // DMAs per thread per stage
  constexpr int NIT = K/32;
  __shared__ unsigned int As[NS*2048];
  __shared__ unsigned int Bs[NS*TN*16];
  const int tid = threadIdx.x;
  int bid = blockIdx.x;
  const int by = 4*(bid&7) + ((bid>>3)&3);   // XCD owns 4 row strips
  const int bx = bid>>5;
  const int bm = by*128, bn = bx*TN;
  const int lane = tid&63, wid = tid>>6;
  const int wr = (wid>>1)*64, wc = (wid&1)*(TN/2);
  const int quad = lane>>4, mr = lane&15;
  const int L4 = lane>>2, Lc = lane&3;
  const int sws = ((L4&3) ^ ((L4>>2)&3));
  const int swr = ((mr&3) ^ ((mr>>2)&3));

  f32x4 acc[4][NJ];
  #pragma unroll
  for(int i=0;i<4;i++)
    #pragma unroll
    for(int j=0;j<NJ;j++) acc[i][j] = (f32x4){0.f,0.f,0.f,0.f};

  auto stage = [&](int kb, int p){
    #pragma unroll
    for(int c2=0; c2<2; c2++){
      int row = (wid*2+c2)*16 + L4;
      const bf16* ap;
      if (DUALA && kb >= K1) ap = Ag2 + (size_t)(bm+row)*LDA2 + (kb-K1);
      else                   ap = Ag  + (size_t)(bm+row)*LDA  + kb;
      gl2lds(ap + (Lc^sws)*8, &As[p*2048 + (wid*2+c2)*256]);
    }
    #pragma unroll
    for(int c2=0; c2<TN/64; c2++){
      int row = (wid*(TN/64)+c2)*16 + L4;
      gl2lds(Bt + (size_t)(bn+row)*LDBT + kb + (Lc^sws)*8,
             &Bs[p*(TN*16) + (wid*(TN/64)+c2)*256]);
    }
  };
  auto compute = [&](int p){
    short8 af[4], bfr[NJ];
    #pragma unroll
    for(int i=0;i<4;i++)
      af[i]  = *(const short8*)&As[p*2048 + (wr + i*16 + mr)*16 + ((quad^swr)*4)];
    #pragma unroll
    for(int j=0;j<NJ;j++)
      bfr[j] = *(const short8*)&Bs[p*(TN*16) + (wc + j*16 + mr)*16 + ((quad^swr)*4)];
    #pragma unroll
    for(int i=0;i<4;i++)
      #pragma unroll
      for(int j=0;j<NJ;j++)
        acc[i][j] = __builtin_amdgcn_mfma_f32_16x16x32_bf16(af[i], bfr[j], acc[i][j], 0,0,0);
  };

  #pragma unroll
  for(int s=0; s<NS-1; s++) stage(32*s, s);
  int p = 0;
  #pragma unroll 1
  for(int it=0; it<NIT-(NS-1); it++){
    waitvm<(NS-2)*D>();
    pipe_barrier();
    stage(32*(it+NS-1), (p+NS-1)&(NS-1));
    compute(p); p=(p+1)&(NS-1);
  }
  waitvm<0>(); pipe_barrier();
  #pragma unroll 1
  for(int r=0; r<NS-1; r++){ compute(p); p=(p+1)&(NS-1); }

  #pragma unroll
  for(int i=0;i<4;i++){
    #pragma unroll
    for(int j=0;j<NJ;j++){
      #pragma unroll
      for(int reg=0; reg<4; reg++){
        int r = bm + wr + i*16 + quad*4 + reg;
        int c = bn + wc + j*16 + mr;
        float v = acc[i][j][reg];
        if (EPI==1){ ((bf16*)Cv)[(size_t)r*LDC + c] = __float2bfloat16(fmaxf(v,0.f)); }
        if (EPI==2){ ((bf16*)Cv)[(size_t)r*LDC + c] = __float2bfloat16(v); }
        if (EPI==4){ float w = v + bias[c];
                     ((float*)Cv)[(size_t)r*LDC + c] = w > 0.f ? w : 0.01f*w; }
      }
    }
  }

  if (WT){   // transposed copy via padded LDS (stride 66 shorts), coalesced out
    __syncthreads();
    bf16* T = (bf16*)As;
    #pragma unroll
    for(int i=0;i<4;i++)
      #pragma unroll
      for(int j=0;j<NJ;j++)
        #pragma unroll
        for(int reg=0; reg<4; reg++){
          int rl = wr + i*16 + quad*4 + reg;
          int cl = wc + j*16 + mr;
          T[rl*66 + cl] = __float2bfloat16(acc[i][j][reg]);
        }
    __syncthreads();
    #pragma unroll
    for(int w=0; w<16; w++){
      int cl = wid*16 + w;
      unsigned int v = (unsigned int)(*(unsigned short*)&T[(2*lane)*66 + cl]) |
                       ((unsigned int)(*(unsigned short*)&T[(2*lane+1)*66 + cl]) << 16);
      *(unsigned int*)&Ct[(size_t)(bn+cl)*4096 + bm + 2*lane] = v;
    }
  }
}

// ---------------------------------------------------------------------------
// el/er (pre-scaled by log2 e)
// ---------------------------------------------------------------------------
__global__ __launch_bounds__(256)
void elr_k(const bf16* __restrict__ feat, const float* __restrict__ al,
           const float* __restrict__ ar, float* __restrict__ el,
           float* __restrict__ er, int H)
{
  __shared__ float sd[256];
  int n = blockIdx.x, t = threadIdx.x, k0 = t*4;
  float accl = 0.f, accr = 0.f;
  #pragma unroll
  for(int q=0;q<4;q++){
    float f = __bfloat162float(feat[(size_t)n*1024 + k0 + q]);
    accl += f * al[k0+q]; accr += f * ar[k0+q];
  }
  int myh = (H==2) ? (k0 >> 9) : 0;
  for(int h=0; h<H; h++){
    float rl = br_sum(myh==h ? accl : 0.f, sd);
    float rr = br_sum(myh==h ? accr : 0.f, sd);
    if(t==0){ el[h*NN+n] = rl*L2E; er[h*NN+n] = rr*L2E; }
  }
}

// ---------------------------------------------------------------------------
// fused column softmax stats + alpha materialization (log2 space).
// XCD-affinity remap: block b -> d = 512*(b&7) + (b>>3), so the XCD that
// writes P rows [512x,512x+512) is the one whose agg blocks read them.
// ---------------------------------------------------------------------------
__global__ __launch_bounds__(256)
void colp_k(const float* __restrict__ el, const float* __restrict__ er,
            const unsigned int* __restrict__ mult2,
            float* __restrict__ cm, float* __restrict__ cinv,
            bf16* __restrict__ P)
{
  __shared__ float sd[256];
  int braw = blockIdx.x & 4095, hs = blockIdx.x >> 12, t = threadIdx.x;
  int d = ((braw&7)<<9) + (braw>>3);
  el += hs*NN; er += hs*NN; cm += hs*NN; cinv += hs*NN;
  float erd = er[d];
  unsigned int bits = mult2[(size_t)d*256 + t];
  float tv[16];
  float mx = -1e30f;
  const float* ep = el + t*16;
  #pragma unroll
  for(int h=0; h<4; h++){
    f32x4 ev = *(const f32x4*)(ep + h*4);
    #pragma unroll
    for(int q2=0;q2<4;q2++){
      int q = h*4 + q2;
      unsigned int mu = (bits >> (2*q)) & 3u;
      float x = ev[q2] + erd;
      x = fmaxf(x, 0.2f*x);
      if (mu == 2u) x += 1.0f;          // log2(2)
      tv[q] = mu ? x : -1e30f;
      mx = fmaxf(mx, tv[q]);
    }
  }
  sd[t] = mx; __syncthreads();
  for(int s=128;s>0;s>>=1){ if(t<s) sd[t]=fmaxf(sd[t],sd[t+s]); __syncthreads(); }
  float M = sd[0]; __syncthreads();
  float sum = 0.f;
  #pragma unroll
  for(int q=0;q<16;q++) sum += (tv[q] > -1e29f) ? __builtin_exp2f(tv[q]-M) : 0.f;
  sum = br_sum(sum, sd);
  if(t==0){ cm[d] = M; cinv[d] = 1.f/sum; }
  if (hs == 0 && P){
    float inv = 1.f/sum;
    unsigned int pk[8];
    #pragma unroll
    for(int h=0; h<4; h++){
      #pragma unroll
      for(int q2=0; q2<4; q2++){
        int q = h*4+q2;
        float v = (tv[q] > -1e29f) ? __builtin_exp2f(tv[q]-M)*inv : 0.f;
        bf16 hb = __float2bfloat16(v);
        unsigned short us = *(unsigned short*)&hb;
        if (q2 & 1) pk[h*2 + (q2>>1)] |= ((unsigned int)us << 16);
        else        pk[h*2 + (q2>>1)]  = (unsigned int)us;
      }
    }
    uint4* dst = (uint4*)(P + (size_t)d*4096 + t*16);
    dst[0] = *(uint4*)&pk[0];
    dst[1] = *(uint4*)&pk[4];
  }
}

// ---------------------------------------------------------------------------
// standalone alpha build (head 1), same XCD-affinity remap
// ---------------------------------------------------------------------------
__global__ __launch_bounds__(256)
void pbuild_k(const float* __restrict__ el, const float* __restrict__ er,
              const float* __restrict__ cm, const float* __restrict__ cinv,
              const unsigned int* __restrict__ mult2, bf16* __restrict__ P)
{
  int braw = blockIdx.x, t = threadIdx.x;
  int d = ((braw&7)<<9) + (braw>>3);
  const float erd = er[d], md = cm[d], invd = cinv[d];
  unsigned int bits = mult2[(size_t)d*256 + t];
  unsigned int pk[8];
  const float* ep = el + t*16;
  #pragma unroll
  for(int h=0; h<4; h++){
    f32x4 ev = *(const f32x4*)(ep + h*4);
    #pragma unroll
    for(int q2=0; q2<4; q2++){
      int q = h*4+q2;
      unsigned int mu = (bits >> (2*q)) & 3u;
      float x = ev[q2] + erd;
      x = fmaxf(x, 0.2f*x);
      float v = __builtin_exp2f(x + (mu>1u ? 1.0f : 0.0f) - md) * invd;
      v = mu ? v : 0.0f;
      bf16 hb = __float2bfloat16(v);
      unsigned short us = *(unsigned short*)&hb;
      if (q2 & 1) pk[h*2 + (q2>>1)] |= ((unsigned int)us << 16);
      else        pk[h*2 + (q2>>1)]  = (unsigned int)us;
    }
  }
  uint4* dst = (uint4*)(P + (size_t)d*4096 + t*16);
  dst[0] = *(uint4*)&pk[0];
  dst[1] = *(uint4*)&pk[4];
}

// ---------------------------------------------------------------------------
// merged classifiers
// ---------------------------------------------------------------------------
__global__ __launch_bounds__(256)
void cls2_k(const float* __restrict__ x3, const float* __restrict__ df,
            const float* __restrict__ c1w, const float* __restrict__ c1b,
            const float* __restrict__ c2w, const float* __restrict__ c2b,
            float* __restrict__ out)
{
  __shared__ float sd[256];
  int b = blockIdx.x, t = threadIdx.x;
  const float* X; const float* Wt; const float* bi; int K, n; float* o;
  if (b < 4096){ X = x3; Wt = c1w; bi = c1b; K = 1024; n = b;      o = out; }
  else         { X = df; Wt = c2w; bi = c2b; K = 2048; n = b-4096; o = out + NN*10; }
  float acc[10] = {};
  for(int k=t; k<K; k+=256){
    float xv = X[(size_t)n*K + k];
    #pragma unroll
    for(int c=0;c<10;c++) acc[c] += xv * Wt[k*10 + c];
  }
  for(int c=0;c<10;c++){
    float r = br_sum(acc[c], sd);
    if(t==0) o[n*10 + c] = r + bi[c];
  }
}

// ---------------------------------------------------------------------------
extern "C" void kernel_launch(void* const* d_in, const int* in_sizes, int n_in,
                              void* d_out, int out_size, void* d_ws, size_t ws_size,
                              hipStream_t stream) {
  (void)in_sizes; (void)n_in; (void)out_size; (void)ws_size;
  const float* df  = (const float*)d_in[0];
  const float* W1  = (const float*)d_in[1];
  const float* al1 = (const float*)d_in[2];
  const float* ar1 = (const float*)d_in[3];
  const float* W2  = (const float*)d_in[4];
  const float* al2 = (const float*)d_in[5];
  const float* ar2 = (const float*)d_in[6];
  const float* lw  = (const float*)d_in[7];
  const float* lb  = (const float*)d_in[8];
  const float* c1w = (const float*)d_in[9];
  const float* c1b = (const float*)d_in[10];
  const float* c2w = (const float*)d_in[11];
  const float* c2b = (const float*)d_in[12];
  float* out = (float*)d_out;

  char* Wp = (char*)d_ws;                                   // peak 88 MB
  bf16* W1tb  = (bf16*)(Wp);                                // 4 MB, dead after feat1
  float* S    = (float*)(Wp);                               // smalls reuse W1tb
  bf16* W2tb  = (bf16*)(Wp + ( 4u<<20));                    // 2 MB
  bf16* lwcat = (bf16*)(Wp + ( 6u<<20));                    // 6 MB [1024][3072]
  unsigned int* mult2 = (unsigned int*)(Wp + (12u<<20));    // 4 MB packed adj
  bf16* dfb   = (bf16*)(Wp + (16u<<20));                    // 16 MB [4096][2048]
  bf16* featb = (bf16*)(Wp + (32u<<20));                    // 8 MB [4096][1024]
  float* x3   = (float*)(Wp + (32u<<20));                   // 16 MB (featb/featT dead)
  bf16* featT = (bf16*)(Wp + (40u<<20));                    // 8 MB [1024][4096]
  bf16* x1b   = (bf16*)(Wp + (48u<<20));                    // 8 MB [4096][1024]
  bf16* x2cat = (bf16*)(Wp + (48u<<20));                    // 8 MB (x1b dead)
  bf16* P     = (bf16*)(Wp + (56u<<20));                    // 32 MB alpha
  float *el1=S, *er1=S+4096, *el2=S+8192, *er2=S+16384;
  float *m1=S+24576, *i1=S+28672, *m2=S+32768, *i2=S+40960;

  // 0) fused prep
  prep_all_k<<<9600,256,0,stream>>>(df, W1, W2, lw, dfb, W1tb, W2tb, lwcat);

  // 1) symmetric adjacency (4-deep pipeline, bank-swizzled)
  adjsym_k<<<528,256,0,stream>>>(dfb, mult2);

  // 2) feat1 = df @ W1 -> bf16 (+ transposed featT in-epilogue)
  gemm_k<2,64,0,2048,2048,2048,1024,0,0,1,4><<<512,256,0,stream>>>(
      dfb, W1tb, featb, nullptr, nullptr, featT);

  // 3) layer-1 scores + fused stats+alpha (P, XCD-affine)
  elr_k<<<NN,256,0,stream>>>(featb, al1, ar1, el1, er1, 1);
  colp_k<<<4096,256,0,stream>>>(el1, er1, mult2, m1, i1, P);

  // 4) x1 = relu(P @ feat1)
  gemm_k<1,64,0,4096,4096,4096,1024,0,0,0,4><<<512,256,0,stream>>>(
      P, featT, x1b, nullptr, nullptr, nullptr);

  // 5) feat2 = x1 @ W2 -> bf16 (+ transposed featT)
  gemm_k<2,64,0,1024,1024,1024,1024,0,0,1,4><<<512,256,0,stream>>>(
      x1b, W2tb, featb, nullptr, nullptr, featT);

  // 6) layer-2 scores, fused stats (both heads) + alpha-h0 (P)
  elr_k<<<NN,256,0,stream>>>(featb, al2, ar2, el2, er2, 2);
  colp_k<<<8192,256,0,stream>>>(el2, er2, mult2, m2, i2, P);

  // 6a) head 0 aggregation -> x2cat[:, :512]  (1 blk/CU -> 8-deep pipeline)
  gemm_k<2,64,0,4096,4096,4096,1024,0,0,0,8><<<256,256,0,stream>>>(
      P, featT, x2cat, nullptr, nullptr, nullptr);

  // 6b) head 1: alpha -> P (XCD-affine), aggregation -> x2cat[:, 512:]
  pbuild_k<<<4096,256,0,stream>>>(el2+NN, er2+NN, m2+NN, i2+NN, mult2, P);
  gemm_k<2,64,0,4096,4096,4096,1024,0,0,0,8><<<256,256,0,stream>>>(
      P, featT + (size_t)512*4096, x2cat + 512, nullptr, nullptr, nullptr);

  // 7) x3 = leaky([df | x2h0+x2h1] @ lin1_w + b, 0.01), dual-A K=3072
  gemm_k<4,64,1,3072,2048,3072,1024,2048,1024,0,4><<<512,256,0,stream>>>(
      dfb, lwcat, x3, lb, x2cat, nullptr);

  // 8) merged classifiers -> f32 out
  cls2_k<<<8192,256,0,stream>>>(x3, df, c1w, c1b, c2w, c2b, out);
}

// Round 11
// 493.907 us; speedup vs baseline: 1.2858x; 1.2858x over previous
//
#include <hip/hip_runtime.h>
#include <hip/hip_bf16.h>

typedef __hip_bfloat16 bf16;
typedef __attribute__((ext_vector_type(8))) short short8;
typedef __attribute__((ext_vector_type(4))) float f32x4;

#define NN 4096
#define L2E 1.4426950408889634f

__device__ inline float br_sum(float v, float* sd){
  int t = threadIdx.x;
  sd[t] = v; __syncthreads();
  for(int s=128; s>0; s>>=1){ if(t<s) sd[t]+=sd[t+s]; __syncthreads(); }
  float r = sd[0]; __syncthreads();
  return r;
}

// async global->LDS, 16B per lane; lds base wave-uniform (HW adds lane*16)
__device__ inline void gl2lds(const bf16* g, unsigned int* lds){
  __builtin_amdgcn_global_load_lds(
      (const __attribute__((address_space(1))) unsigned int*)g,
      (__attribute__((address_space(3))) unsigned int*)lds, 16, 0, 0);
}

// wait until <= N of this thread's vmem ops outstanding
template<int N> __device__ inline void waitvm(){
  if constexpr (N==0)       asm volatile("s_waitcnt vmcnt(0)" ::: "memory");
  else if constexpr (N==4)  asm volatile("s_waitcnt vmcnt(4)" ::: "memory");
  else if constexpr (N==6)  asm volatile("s_waitcnt vmcnt(6)" ::: "memory");
  else if constexpr (N==18) asm volatile("s_waitcnt vmcnt(18)" ::: "memory");
}
__device__ inline void pipe_barrier(){
  __builtin_amdgcn_s_barrier();
  asm volatile("" ::: "memory");
}

// ---------------------------------------------------------------------------
// fused prep: blocks 0..8191 cvt df->bf16; 8192.. weight transposes
// ---------------------------------------------------------------------------
__global__ __launch_bounds__(256)
void prep_all_k(const float* __restrict__ df, const float* __restrict__ W1,
                const float* __restrict__ W2, const float* __restrict__ lw,
                bf16* __restrict__ dfb, bf16* __restrict__ W1tb,
                bf16* __restrict__ W2tb, bf16* __restrict__ lwcat)
{
  int b = blockIdx.x, t = threadIdx.x;
  if (b < 8192){
    int i = (b*256 + t)*4;
    f32x4 v = *(const f32x4*)(df + i);
    #pragma unroll
    for(int q=0;q<4;q++) dfb[i+q] = __float2bfloat16(v[q]);
    return;
  }
  b -= 8192;
  const float* src; bf16* dst; int rb, cb, dstld; bool dup=false;
  if (b < 512){            src=W1; dst=W1tb;  rb=(b>>4)<<6; cb=(b&15)<<6; dstld=2048; }
  else if (b < 768){ b-=512; src=W2; dst=W2tb; rb=(b>>4)<<6; cb=(b&15)<<6; dstld=1024; }
  else { b-=768; src=lw; dst=lwcat; rb=(b>>4)<<6; cb=(b&15)<<6; dstld=3072; dup=(rb>=2048); }
  __shared__ bf16 tile[64][65];
  #pragma unroll
  for(int i=0;i<16;i++){
    int lin=i*256+t, tr=lin>>6, tc=lin&63;
    tile[tr][tc] = __float2bfloat16(src[(size_t)(rb+tr)*1024 + cb+tc]);
  }
  __syncthreads();
  #pragma unroll
  for(int i=0;i<16;i++){
    int lin=i*256+t, tc=lin>>6, tr=lin&63;
    bf16 v = tile[tr][tc];
    dst[(size_t)(cb+tc)*dstld + rb+tr] = v;
    if(dup) dst[(size_t)(cb+tc)*dstld + rb+tr + 512] = v;
  }
}

// ---------------------------------------------------------------------------
// adjacency body: one upper-tri 128x128 block of sign(df@df^T), 3-buffer
// 2-ahead pipeline (R9-proven), mirror-packed epilogue.  SH: 12288 u32.
// ---------------------------------------------------------------------------
__device__ __forceinline__
void adj_body(const bf16* __restrict__ A, unsigned int* __restrict__ Cm,
              unsigned int* SH, int idx)
{
  unsigned int* As = SH;          // 3*2048
  unsigned int* Bs = SH + 6144;   // 3*2048
  const int tid = threadIdx.x;
  int by = (int)((65.0f - sqrtf(4225.0f - 8.0f*(float)idx)) * 0.5f);
  while ((by+1)*(65-(by+1))/2 <= idx) by++;
  while (by*(65-by)/2 > idx) by--;
  int bx = by + (idx - by*(65-by)/2);
  const int bm = by*128, bn = bx*128;
  const int lane = tid&63, wid = tid>>6;
  const int wr = (wid>>1)*64, wc = (wid&1)*64;
  const int quad = lane>>4, mr = lane&15;
  const int L4 = lane>>2, Lc = lane&3;

  f32x4 acc[4][4];
  #pragma unroll
  for(int i=0;i<4;i++)
    #pragma unroll
    for(int j=0;j<4;j++) acc[i][j] = (f32x4){0.f,0.f,0.f,0.f};

  auto stage = [&](int kb, int p){
    #pragma unroll
    for(int c2=0; c2<2; c2++){
      int row = (wid*2+c2)*16 + L4;
      gl2lds(A + (size_t)(bm+row)*2048 + kb + Lc*8, &As[p*2048 + (wid*2+c2)*256]);
      gl2lds(A + (size_t)(bn+row)*2048 + kb + Lc*8, &Bs[p*2048 + (wid*2+c2)*256]);
    }
  };
  auto compute = [&](int p){
    short8 af[4], bfr[4];
    #pragma unroll
    for(int i=0;i<4;i++)  af[i]  = *(const short8*)&As[p*2048 + (wr + i*16 + mr)*16 + quad*4];
    #pragma unroll
    for(int j=0;j<4;j++)  bfr[j] = *(const short8*)&Bs[p*2048 + (wc + j*16 + mr)*16 + quad*4];
    #pragma unroll
    for(int i=0;i<4;i++)
      #pragma unroll
      for(int j=0;j<4;j++)
        acc[i][j] = __builtin_amdgcn_mfma_f32_16x16x32_bf16(af[i], bfr[j], acc[i][j], 0,0,0);
  };

  stage(0,0); stage(32,1);
  int p = 0;
  #pragma unroll 1
  for(int it=0; it<63; it++){
    waitvm<4>();
    pipe_barrier();
    if (it+2 < 64) stage(32*(it+2), p==0?2:p-1);
    compute(p);
    p = (p==2)?0:p+1;
  }
  waitvm<0>();
  pipe_barrier();
  compute(p);

  #pragma unroll
  for(int i=0;i<4;i++){
    #pragma unroll
    for(int j=0;j<4;j++){
      int cbase = bn + wc + j*16;
      unsigned long long b[4];
      #pragma unroll
      for(int reg=0; reg<4; reg++){
        float v = acc[i][j][reg];
        unsigned long long msk = __ballot(v > 0.f);
        b[reg] = msk;
        if (mr == 0){                       // direct: row r, 16 cols
          int r = bm + wr + i*16 + quad*4 + reg;
          unsigned int x = (unsigned int)(msk >> (quad*16)) & 0xFFFFu;
          x = (x | (x << 8)) & 0x00FF00FFu;
          x = (x | (x << 4)) & 0x0F0F0F0Fu;
          x = (x | (x << 2)) & 0x33333333u;
          x = (x | (x << 1)) & 0x55555555u;
          if (r >= cbase && r < cbase + 16) x += 1u << (2*(r - cbase));
          Cm[(size_t)r*256 + (cbase>>4)] = x;
        }
      }
      if (bx > by){                         // mirror: row c (transposed bits)
        unsigned int x = 0;
        #pragma unroll
        for(int reg=0; reg<4; reg++){
          unsigned long long t = (b[reg] >> mr) & 0x0001000100010001ULL;
          unsigned int f = (unsigned int)((t | (t>>15) | (t>>30) | (t>>45)) & 0xFULL);
          x |= ((f&1u) | ((f&2u)<<7) | ((f&4u)<<14) | ((f&8u)<<21)) << (2*reg);
        }
        if (quad == 0){
          int c = cbase + mr;
          Cm[(size_t)c*256 + ((bm + wr + i*16)>>4)] = x;
        }
      }
    }
  }
}

// ---------------------------------------------------------------------------
// GEMM body: C = A @ Bt^T, 128 x TN tile, NS-deep pipelined async staging,
// XCD-aware block swizzle.  DUALA: A -> Ag2 at k>=K1.  WT: also emit
// transposed bf16 copy to Ct.  EPI: 1 relu->bf16 | 2 bf16 | 4 +bias+leaky.
// NS must be a power of 2.  SH: NS*2048 + NS*TN*16 u32.
// ---------------------------------------------------------------------------
template<int EPI, int TN, int DUALA, int K, int LDA, int LDBT, int LDC,
         int K1, int LDA2, int WT, int NS>
__device__ __forceinline__
void gemm_body(const bf16* __restrict__ Ag, const bf16* __restrict__ Bt,
               void* __restrict__ Cv, const float* __restrict__ bias,
               const bf16* __restrict__ Ag2, bf16* __restrict__ Ct,
               unsigned int* SH, int bid)
{
  constexpr int NJ  = TN/32;
  constexpr int D   = 2 + TN/64;     // DMAs per thread per stage
  constexpr int NIT = K/32;
  unsigned int* As = SH;
  unsigned int* Bs = SH + NS*2048;
  const int tid = threadIdx.x;
  const int by = 4*(bid&7) + ((bid>>3)&3);   // XCD owns 4 row strips
  const int bx = bid>>5;
  const int bm = by*128, bn = bx*TN;
  const int lane = tid&63, wid = tid>>6;
  const int wr = (wid>>1)*64, wc = (wid&1)*(TN/2);
  const int quad = lane>>4, mr = lane&15;
  const int L4 = lane>>2, Lc = lane&3;

  f32x4 acc[4][NJ];
  #pragma unroll
  for(int i=0;i<4;i++)
    #pragma unroll
    for(int j=0;j<NJ;j++) acc[i][j] = (f32x4){0.f,0.f,0.f,0.f};

  auto stage = [&](int kb, int p){
    #pragma unroll
    for(int c2=0; c2<2; c2++){
      int row = (wid*2+c2)*16 + L4;
      const bf16* ap;
      if (DUALA && kb >= K1) ap = Ag2 + (size_t)(bm+row)*LDA2 + (kb-K1);
      else                   ap = Ag  + (size_t)(bm+row)*LDA  + kb;
      gl2lds(ap + Lc*8, &As[p*2048 + (wid*2+c2)*256]);
    }
    #pragma unroll
    for(int c2=0; c2<TN/64; c2++){
      int row = (wid*(TN/64)+c2)*16 + L4;
      gl2lds(Bt + (size_t)(bn+row)*LDBT + kb + Lc*8,
             &Bs[p*(TN*16) + (wid*(TN/64)+c2)*256]);
    }
  };
  auto compute = [&](int p){
    short8 af[4], bfr[NJ];
    #pragma unroll
    for(int i=0;i<4;i++)
      af[i]  = *(const short8*)&As[p*2048 + (wr + i*16 + mr)*16 + quad*4];
    #pragma unroll
    for(int j=0;j<NJ;j++)
      bfr[j] = *(const short8*)&Bs[p*(TN*16) + (wc + j*16 + mr)*16 + quad*4];
    #pragma unroll
    for(int i=0;i<4;i++)
      #pragma unroll
      for(int j=0;j<NJ;j++)
        acc[i][j] = __builtin_amdgcn_mfma_f32_16x16x32_bf16(af[i], bfr[j], acc[i][j], 0,0,0);
  };

  #pragma unroll
  for(int s=0; s<NS-1; s++) stage(32*s, s);
  int p = 0;
  #pragma unroll 1
  for(int it=0; it<NIT-(NS-1); it++){
    waitvm<(NS-2)*D>();
    pipe_barrier();
    stage(32*(it+NS-1), (p+NS-1)&(NS-1));
    compute(p); p=(p+1)&(NS-1);
  }
  waitvm<0>(); pipe_barrier();
  #pragma unroll 1
  for(int r=0; r<NS-1; r++){ compute(p); p=(p+1)&(NS-1); }

  #pragma unroll
  for(int i=0;i<4;i++){
    #pragma unroll
    for(int j=0;j<NJ;j++){
      #pragma unroll
      for(int reg=0; reg<4; reg++){
        int r = bm + wr + i*16 + quad*4 + reg;
        int c = bn + wc + j*16 + mr;
        float v = acc[i][j][reg];
        if (EPI==1){ ((bf16*)Cv)[(size_t)r*LDC + c] = __float2bfloat16(fmaxf(v,0.f)); }
        if (EPI==2){ ((bf16*)Cv)[(size_t)r*LDC + c] = __float2bfloat16(v); }
        if (EPI==4){ float w = v + bias[c];
                     ((float*)Cv)[(size_t)r*LDC + c] = w > 0.f ? w : 0.01f*w; }
      }
    }
  }

  if (WT){   // transposed copy via padded LDS (stride 66 shorts), coalesced out
    __syncthreads();
    bf16* T = (bf16*)SH;
    #pragma unroll
    for(int i=0;i<4;i++)
      #pragma unroll
      for(int j=0;j<NJ;j++)
        #pragma unroll
        for(int reg=0; reg<4; reg++){
          int rl = wr + i*16 + quad*4 + reg;
          int cl = wc + j*16 + mr;
          T[rl*66 + cl] = __float2bfloat16(acc[i][j][reg]);
        }
    __syncthreads();
    #pragma unroll
    for(int w=0; w<16; w++){
      int cl = wid*16 + w;
      unsigned int v = (unsigned int)(*(unsigned short*)&T[(2*lane)*66 + cl]) |
                       ((unsigned int)(*(unsigned short*)&T[(2*lane+1)*66 + cl]) << 16);
      *(unsigned int*)&Ct[(size_t)(bn+cl)*4096 + bm + 2*lane] = v;
    }
  }
}

// standalone GEMM kernel
template<int EPI, int TN, int DUALA, int K, int LDA, int LDBT, int LDC,
         int K1, int LDA2, int WT, int NS>
__global__ __launch_bounds__(256)
void gemm_k(const bf16* __restrict__ Ag, const bf16* __restrict__ Bt,
            void* __restrict__ Cv, const float* __restrict__ bias,
            const bf16* __restrict__ Ag2, bf16* __restrict__ Ct)
{
  __shared__ unsigned int SH[NS*2048 + NS*TN*16];
  gemm_body<EPI,TN,DUALA,K,LDA,LDBT,LDC,K1,LDA2,WT,NS>(
      Ag, Bt, Cv, bias, Ag2, Ct, SH, blockIdx.x);
}

// ---------------------------------------------------------------------------
// fused adjacency + feat1: blocks 0..527 = upper-tri adjacency tiles,
// 528..1039 = feat1 GEMM tiles.  Independent work, mixed co-residency
// (48 KB LDS each -> 3 blocks/CU) so feat1's MFMA fills adj's stalls.
// ---------------------------------------------------------------------------
__global__ __launch_bounds__(256)
void adjfeat_k(const bf16* __restrict__ dfb, unsigned int* __restrict__ mult2,
               const bf16* __restrict__ W1tb, bf16* __restrict__ featb,
               bf16* __restrict__ featT)
{
  __shared__ unsigned int SH[12288];   // 48 KB union
  int b = blockIdx.x;
  if (b < 528){
    adj_body(dfb, mult2, SH, b);
  } else {
    gemm_body<2,64,0,2048,2048,2048,1024,0,0,1,4>(
        dfb, W1tb, featb, nullptr, nullptr, featT, SH, b-528);
  }
}

// ---------------------------------------------------------------------------
// el/er (pre-scaled by log2 e)
// ---------------------------------------------------------------------------
__global__ __launch_bounds__(256)
void elr_k(const bf16* __restrict__ feat, const float* __restrict__ al,
           const float* __restrict__ ar, float* __restrict__ el,
           float* __restrict__ er, int H)
{
  __shared__ float sd[256];
  int n = blockIdx.x, t = threadIdx.x, k0 = t*4;
  float accl = 0.f, accr = 0.f;
  #pragma unroll
  for(int q=0;q<4;q++){
    float f = __bfloat162float(feat[(size_t)n*1024 + k0 + q]);
    accl += f * al[k0+q]; accr += f * ar[k0+q];
  }
  int myh = (H==2) ? (k0 >> 9) : 0;
  for(int h=0; h<H; h++){
    float rl = br_sum(myh==h ? accl : 0.f, sd);
    float rr = br_sum(myh==h ? accr : 0.f, sd);
    if(t==0){ el[h*NN+n] = rl*L2E; er[h*NN+n] = rr*L2E; }
  }
}

// ---------------------------------------------------------------------------
// fused column softmax stats + alpha materialization (log2 space).
// grid = HS*4096, hs = blockIdx>>12; P written only by hs==0 blocks.
// ---------------------------------------------------------------------------
__global__ __launch_bounds__(256)
void colp_k(const float* __restrict__ el, const float* __restrict__ er,
            const unsigned int* __restrict__ mult2,
            float* __restrict__ cm, float* __restrict__ cinv,
            bf16* __restrict__ P)
{
  __shared__ float sd[256];
  int d = blockIdx.x & 4095, hs = blockIdx.x >> 12, t = threadIdx.x;
  el += hs*NN; er += hs*NN; cm += hs*NN; cinv += hs*NN;
  float erd = er[d];
  unsigned int bits = mult2[(size_t)d*256 + t];
  float tv[16];
  float mx = -1e30f;
  const float* ep = el + t*16;
  #pragma unroll
  for(int h=0; h<4; h++){
    f32x4 ev = *(const f32x4*)(ep + h*4);
    #pragma unroll
    for(int q2=0;q2<4;q2++){
      int q = h*4 + q2;
      unsigned int mu = (bits >> (2*q)) & 3u;
      float x = ev[q2] + erd;
      x = fmaxf(x, 0.2f*x);
      if (mu == 2u) x += 1.0f;          // log2(2)
      tv[q] = mu ? x : -1e30f;
      mx = fmaxf(mx, tv[q]);
    }
  }
  sd[t] = mx; __syncthreads();
  for(int s=128;s>0;s>>=1){ if(t<s) sd[t]=fmaxf(sd[t],sd[t+s]); __syncthreads(); }
  float M = sd[0]; __syncthreads();
  float sum = 0.f;
  #pragma unroll
  for(int q=0;q<16;q++) sum += (tv[q] > -1e29f) ? __builtin_exp2f(tv[q]-M) : 0.f;
  sum = br_sum(sum, sd);
  if(t==0){ cm[d] = M; cinv[d] = 1.f/sum; }
  if (hs == 0 && P){
    float inv = 1.f/sum;
    unsigned int pk[8];
    #pragma unroll
    for(int h=0; h<4; h++){
      #pragma unroll
      for(int q2=0; q2<4; q2++){
        int q = h*4+q2;
        float v = (tv[q] > -1e29f) ? __builtin_exp2f(tv[q]-M)*inv : 0.f;
        bf16 hb = __float2bfloat16(v);
        unsigned short us = *(unsigned short*)&hb;
        if (q2 & 1) pk[h*2 + (q2>>1)] |= ((unsigned int)us << 16);
        else        pk[h*2 + (q2>>1)]  = (unsigned int)us;
      }
    }
    uint4* dst = (uint4*)(P + (size_t)d*4096 + t*16);
    dst[0] = *(uint4*)&pk[0];
    dst[1] = *(uint4*)&pk[4];
  }
}

// ---------------------------------------------------------------------------
// standalone alpha build (head 1, after head-0 agg frees P)
// ---------------------------------------------------------------------------
__global__ __launch_bounds__(256)
void pbuild_k(const float* __restrict__ el, const float* __restrict__ er,
              const float* __restrict__ cm, const float* __restrict__ cinv,
              const unsigned int* __restrict__ mult2, bf16* __restrict__ P)
{
  int d = blockIdx.x, t = threadIdx.x;
  const float erd = er[d], md = cm[d], invd = cinv[d];
  unsigned int bits = mult2[(size_t)d*256 + t];
  unsigned int pk[8];
  const float* ep = el + t*16;
  #pragma unroll
  for(int h=0; h<4; h++){
    f32x4 ev = *(const f32x4*)(ep + h*4);
    #pragma unroll
    for(int q2=0; q2<4; q2++){
      int q = h*4+q2;
      unsigned int mu = (bits >> (2*q)) & 3u;
      float x = ev[q2] + erd;
      x = fmaxf(x, 0.2f*x);
      float v = __builtin_exp2f(x + (mu>1u ? 1.0f : 0.0f) - md) * invd;
      v = mu ? v : 0.0f;
      bf16 hb = __float2bfloat16(v);
      unsigned short us = *(unsigned short*)&hb;
      if (q2 & 1) pk[h*2 + (q2>>1)] |= ((unsigned int)us << 16);
      else        pk[h*2 + (q2>>1)]  = (unsigned int)us;
    }
  }
  uint4* dst = (uint4*)(P + (size_t)d*4096 + t*16);
  dst[0] = *(uint4*)&pk[0];
  dst[1] = *(uint4*)&pk[4];
}

// ---------------------------------------------------------------------------
// merged classifiers
// ---------------------------------------------------------------------------
__global__ __launch_bounds__(256)
void cls2_k(const float* __restrict__ x3, const float* __restrict__ df,
            const float* __restrict__ c1w, const float* __restrict__ c1b,
            const float* __restrict__ c2w, const float* __restrict__ c2b,
            float* __restrict__ out)
{
  __shared__ float sd[256];
  int b = blockIdx.x, t = threadIdx.x;
  const float* X; const float* Wt; const float* bi; int K, n; float* o;
  if (b < 4096){ X = x3; Wt = c1w; bi = c1b; K = 1024; n = b;      o = out; }
  else         { X = df; Wt = c2w; bi = c2b; K = 2048; n = b-4096; o = out + NN*10; }
  float acc[10] = {};
  for(int k=t; k<K; k+=256){
    float xv = X[(size_t)n*K + k];
    #pragma unroll
    for(int c=0;c<10;c++) acc[c] += xv * Wt[k*10 + c];
  }
  for(int c=0;c<10;c++){
    float r = br_sum(acc[c], sd);
    if(t==0) o[n*10 + c] = r + bi[c];
  }
}

// ---------------------------------------------------------------------------
extern "C" void kernel_launch(void* const* d_in, const int* in_sizes, int n_in,
                              void* d_out, int out_size, void* d_ws, size_t ws_size,
                              hipStream_t stream) {
  (void)in_sizes; (void)n_in; (void)out_size; (void)ws_size;
  const float* df  = (const float*)d_in[0];
  const float* W1  = (const float*)d_in[1];
  const float* al1 = (const float*)d_in[2];
  const float* ar1 = (const float*)d_in[3];
  const float* W2  = (const float*)d_in[4];
  const float* al2 = (const float*)d_in[5];
  const float* ar2 = (const float*)d_in[6];
  const float* lw  = (const float*)d_in[7];
  const float* lb  = (const float*)d_in[8];
  const float* c1w = (const float*)d_in[9];
  const float* c1b = (const float*)d_in[10];
  const float* c2w = (const float*)d_in[11];
  const float* c2b = (const float*)d_in[12];
  float* out = (float*)d_out;

  char* Wp = (char*)d_ws;                                   // peak 88 MB
  bf16* W1tb  = (bf16*)(Wp);                                // 4 MB, dead after feat1
  float* S    = (float*)(Wp);                               // smalls reuse W1tb
  bf16* W2tb  = (bf16*)(Wp + ( 4u<<20));                    // 2 MB
  bf16* lwcat = (bf16*)(Wp + ( 6u<<20));                    // 6 MB [1024][3072]
  unsigned int* mult2 = (unsigned int*)(Wp + (12u<<20));    // 4 MB packed adj
  bf16* dfb   = (bf16*)(Wp + (16u<<20));                    // 16 MB [4096][2048]
  bf16* featb = (bf16*)(Wp + (32u<<20));                    // 8 MB [4096][1024]
  float* x3   = (float*)(Wp + (32u<<20));                   // 16 MB (featb/featT dead)
  bf16* featT = (bf16*)(Wp + (40u<<20));                    // 8 MB [1024][4096]
  bf16* x1b   = (bf16*)(Wp + (48u<<20));                    // 8 MB [4096][1024]
  bf16* x2cat = (bf16*)(Wp + (48u<<20));                    // 8 MB (x1b dead)
  bf16* P     = (bf16*)(Wp + (56u<<20));                    // 32 MB alpha
  float *el1=S, *er1=S+4096, *el2=S+8192, *er2=S+16384;
  float *m1=S+24576, *i1=S+28672, *m2=S+32768, *i2=S+40960;

  // 0) fused prep
  prep_all_k<<<9600,256,0,stream>>>(df, W1, W2, lw, dfb, W1tb, W2tb, lwcat);

  // 1+2) fused: symmetric adjacency (528 blocks) + feat1 GEMM (512 blocks)
  adjfeat_k<<<1040,256,0,stream>>>(dfb, mult2, W1tb, featb, featT);

  // 3) layer-1 scores + fused stats+alpha (P)
  elr_k<<<NN,256,0,stream>>>(featb, al1, ar1, el1, er1, 1);
  colp_k<<<4096,256,0,stream>>>(el1, er1, mult2, m1, i1, P);

  // 4) x1 = relu(P @ feat1)
  gemm_k<1,64,0,4096,4096,4096,1024,0,0,0,4><<<512,256,0,stream>>>(
      P, featT, x1b, nullptr, nullptr, nullptr);

  // 5) feat2 = x1 @ W2 -> bf16 (+ transposed featT)
  gemm_k<2,64,0,1024,1024,1024,1024,0,0,1,4><<<512,256,0,stream>>>(
      x1b, W2tb, featb, nullptr, nullptr, featT);

  // 6) layer-2 scores, fused stats (both heads) + alpha-h0 (P)
  elr_k<<<NN,256,0,stream>>>(featb, al2, ar2, el2, er2, 2);
  colp_k<<<8192,256,0,stream>>>(el2, er2, mult2, m2, i2, P);

  // 6a) head 0 aggregation -> x2cat[:, :512]  (1 blk/CU -> 8-deep pipeline)
  gemm_k<2,64,0,4096,4096,4096,1024,0,0,0,8><<<256,256,0,stream>>>(
      P, featT, x2cat, nullptr, nullptr, nullptr);

  // 6b) head 1: alpha -> P, aggregation -> x2cat[:, 512:]
  pbuild_k<<<4096,256,0,stream>>>(el2+NN, er2+NN, m2+NN, i2+NN, mult2, P);
  gemm_k<2,64,0,4096,4096,4096,1024,0,0,0,8><<<256,256,0,stream>>>(
      P, featT + (size_t)512*4096, x2cat + 512, nullptr, nullptr, nullptr);

  // 7) x3 = leaky([df | x2h0+x2h1] @ lin1_w + b, 0.01), dual-A K=3072
  gemm_k<4,64,1,3072,2048,3072,1024,2048,1024,0,4><<<512,256,0,stream>>>(
      dfb, lwcat, x3, lb, x2cat, nullptr);

  // 8) merged classifiers -> f32 out
  cls2_k<<<8192,256,0,stream>>>(x3, df, c1w, c1b, c2w, c2b, out);
}